// Round 3
// baseline (6776.696 us; speedup 1.0000x reference)
//
#include <hip/hip_runtime.h>
#include <cstddef>

#define LSEQ 2048

static __device__ __forceinline__ float siluf(float x) { return x / (1.f + __expf(-x)); }

// ---------------------------------------------------------------------------
// FFT filter kernel: per (b,d) channel, length-2048 complex FFT in LDS.
// Forward DIF (natural -> bit-reversed), pointwise filter in bit-reversed
// order, inverse DIT (bit-reversed -> natural). Writes irfft(rfft(x)*W) + x.
// ---------------------------------------------------------------------------
__global__ __launch_bounds__(256) void fft_filter_kernel(
    const float* __restrict__ x, const float* __restrict__ filt_w,
    float* __restrict__ out) {
  int b = blockIdx.x >> 7, d = blockIdx.x & 127;
  __shared__ float2 A[2048];
  const float* xp = x + (size_t)b * LSEQ * 128 + d;
  for (int i = threadIdx.x; i < 2048; i += 256) {
    A[i] = make_float2(xp[(size_t)i * 128], 0.f);
  }
  // forward DIF, twiddle e^{-2*pi*i*j/len}
  for (int s = 11; s >= 1; --s) {
    int len = 1 << s, half = 1 << (s - 1);
    __syncthreads();
    for (int idx = threadIdx.x; idx < 1024; idx += 256) {
      int j = idx & (half - 1);
      int blk = idx >> (s - 1);
      int i0 = (blk << s) + j, i1 = i0 + half;
      float si, co;
      sincospif(-2.f * (float)j / (float)len, &si, &co);
      float2 u = A[i0], v = A[i1];
      A[i0] = make_float2(u.x + v.x, u.y + v.y);
      float tx = u.x - v.x, ty = u.y - v.y;
      A[i1] = make_float2(tx * co - ty * si, tx * si + ty * co);
    }
  }
  __syncthreads();
  // filter multiply; storage index i holds X[rev(i)]
  for (int i = threadIdx.x; i < 2048; i += 256) {
    int k = (int)(__brev((unsigned)i) >> 21);
    float wr, wi;
    if (k <= 1024) {
      wr = filt_w[(size_t)k * 256 + d * 2];
      wi = filt_w[(size_t)k * 256 + d * 2 + 1];
    } else {
      int k2 = 2048 - k;
      wr = filt_w[(size_t)k2 * 256 + d * 2];
      wi = -filt_w[(size_t)k2 * 256 + d * 2 + 1];
    }
    float2 v = A[i];
    A[i] = make_float2(v.x * wr - v.y * wi, v.x * wi + v.y * wr);
  }
  // inverse DIT, twiddle e^{+2*pi*i*j/len}
  for (int s = 1; s <= 11; ++s) {
    int len = 1 << s, half = 1 << (s - 1);
    __syncthreads();
    for (int idx = threadIdx.x; idx < 1024; idx += 256) {
      int j = idx & (half - 1);
      int blk = idx >> (s - 1);
      int i0 = (blk << s) + j, i1 = i0 + half;
      float si, co;
      sincospif(2.f * (float)j / (float)len, &si, &co);
      float2 u = A[i0], v = A[i1];
      float tx = v.x * co - v.y * si, ty = v.x * si + v.y * co;
      A[i0] = make_float2(u.x + tx, u.y + ty);
      A[i1] = make_float2(u.x - tx, u.y - ty);
    }
  }
  __syncthreads();
  const float inv_n = 1.f / 2048.f;
  for (int i = threadIdx.x; i < 2048; i += 256) {
    out[((size_t)b * LSEQ + i) * 128 + d] = A[i].x * inv_n + xp[(size_t)i * 128];
  }
}

// ---------------------------------------------------------------------------
// LayerNorm over 128 features; one wave per row. out = LN(x (+res)) * w + b
// ---------------------------------------------------------------------------
__global__ __launch_bounds__(256) void ln_kernel(
    const float* __restrict__ x, const float* __restrict__ res,
    const float* __restrict__ w, const float* __restrict__ b,
    float* __restrict__ out, float eps) {
  int row = blockIdx.x * 4 + (threadIdx.x >> 6);
  int lane = threadIdx.x & 63;
  size_t o = (size_t)row * 128;
  float v0 = x[o + lane], v1 = x[o + lane + 64];
  if (res) { v0 += res[o + lane]; v1 += res[o + lane + 64]; }
  float s = v0 + v1, q = v0 * v0 + v1 * v1;
  for (int ofs = 32; ofs > 0; ofs >>= 1) {
    s += __shfl_xor(s, ofs);
    q += __shfl_xor(q, ofs);
  }
  float mean = s * (1.f / 128.f);
  float var = q * (1.f / 128.f) - mean * mean;
  float inv = rsqrtf(var + eps);
  out[o + lane] = (v0 - mean) * inv * w[lane] + b[lane];
  out[o + lane + 64] = (v1 - mean) * inv * w[lane + 64] + b[lane + 64];
}

// h = LN(fs + h; fw,fb) + LN(bs + h; bw,bb), eps=1e-5, in place on h
__global__ __launch_bounds__(256) void combine_ln_kernel(
    float* __restrict__ h, const float* __restrict__ fs, const float* __restrict__ bs,
    const float* __restrict__ fw, const float* __restrict__ fb,
    const float* __restrict__ bw, const float* __restrict__ bb) {
  int row = blockIdx.x * 4 + (threadIdx.x >> 6);
  int lane = threadIdx.x & 63;
  size_t o = (size_t)row * 128;
  float h0 = h[o + lane], h1 = h[o + lane + 64];
  float f0 = fs[o + lane] + h0, f1 = fs[o + lane + 64] + h1;
  float g0 = bs[o + lane] + h0, g1 = bs[o + lane + 64] + h1;
  float s1 = f0 + f1, q1 = f0 * f0 + f1 * f1;
  float s2 = g0 + g1, q2 = g0 * g0 + g1 * g1;
  for (int ofs = 32; ofs > 0; ofs >>= 1) {
    s1 += __shfl_xor(s1, ofs); q1 += __shfl_xor(q1, ofs);
    s2 += __shfl_xor(s2, ofs); q2 += __shfl_xor(q2, ofs);
  }
  float m1 = s1 * (1.f / 128.f), v1 = q1 * (1.f / 128.f) - m1 * m1;
  float m2 = s2 * (1.f / 128.f), v2 = q2 * (1.f / 128.f) - m2 * m2;
  float i1 = rsqrtf(v1 + 1e-5f), i2 = rsqrtf(v2 + 1e-5f);
  h[o + lane] = (f0 - m1) * i1 * fw[lane] + fb[lane] +
                (g0 - m2) * i2 * bw[lane] + bb[lane];
  h[o + lane + 64] = (f1 - m1) * i1 * fw[lane + 64] + fb[lane + 64] +
                     (g1 - m2) * i2 * bw[lane + 64] + bb[lane + 64];
}

// ---------------------------------------------------------------------------
// Generic fp32 GEMM: Out[R, N] = X[R, K] @ W[N, K]^T (+ bias)
// 64x64 tile, 256 threads, 4x4 micro-tile. grid = (N/64 ceil, R/64)
// ---------------------------------------------------------------------------
__global__ __launch_bounds__(256) void gemm_kernel(
    const float* __restrict__ X, const float* __restrict__ W,
    const float* __restrict__ bias, float* __restrict__ Out, int N, int K) {
  __shared__ float Xs[16][65];
  __shared__ float Ws[16][65];
  int tx = threadIdx.x & 15, ty = threadIdx.x >> 4;
  int n0 = blockIdx.x * 64, m0 = blockIdx.y * 64;
  float acc[4][4] = {};
  for (int k0 = 0; k0 < K; k0 += 16) {
    for (int i = threadIdx.x; i < 1024; i += 256) {
      int r = i >> 4, c = i & 15;
      Xs[c][r] = X[(size_t)(m0 + r) * K + k0 + c];
      int n = n0 + r;
      Ws[c][r] = (n < N) ? W[(size_t)n * K + k0 + c] : 0.f;
    }
    __syncthreads();
#pragma unroll
    for (int c = 0; c < 16; ++c) {
      float a[4], bb[4];
#pragma unroll
      for (int i = 0; i < 4; ++i) a[i] = Xs[c][ty * 4 + i];
#pragma unroll
      for (int j = 0; j < 4; ++j) bb[j] = Ws[c][tx * 4 + j];
#pragma unroll
      for (int i = 0; i < 4; ++i)
#pragma unroll
        for (int j = 0; j < 4; ++j) acc[i][j] += a[i] * bb[j];
    }
    __syncthreads();
  }
#pragma unroll
  for (int i = 0; i < 4; ++i) {
    int m = m0 + ty * 4 + i;
#pragma unroll
    for (int j = 0; j < 4; ++j) {
      int n = n0 + tx * 4 + j;
      if (n < N) {
        float v = acc[i][j] + (bias ? bias[n] : 0.f);
        Out[(size_t)m * N + n] = v;
      }
    }
  }
}

// ---------------------------------------------------------------------------
// Causal depthwise conv(k=4) + bias + SiLU. dir=0: taps l-3+j ; dir=1: l+3-j
// xz layout (R, 512), channels 0..255 are xc. u layout (R, 256). grid = R.
// ---------------------------------------------------------------------------
__global__ __launch_bounds__(256) void conv_silu_kernel(
    const float* __restrict__ xz, const float* __restrict__ cw,
    const float* __restrict__ cb, float* __restrict__ u, int dir) {
  int idx = blockIdx.x * 256 + threadIdx.x;
  int c = idx & 255, bl = idx >> 8;
  int l = bl & (LSEQ - 1), b = bl >> 11;
  float acc = cb[c];
#pragma unroll
  for (int j = 0; j < 4; ++j) {
    int ln = dir ? (l + 3 - j) : (l - 3 + j);
    if (ln >= 0 && ln < LSEQ)
      acc += cw[c * 4 + j] * xz[((size_t)b * LSEQ + ln) * 512 + c];
  }
  u[(size_t)bl * 256 + c] = siluf(acc);
}

// ---------------------------------------------------------------------------
// Selective scan. Block = (b, 16-channel group); thread = (channel, state).
// Chunks of 64 timesteps staged in LDS; delta computed on the fly from dt.
// Epilogue fuses y = (scan_y + u*Dp) * silu(z). grid = NB*16.
// ---------------------------------------------------------------------------
__global__ __launch_bounds__(256) void scan_kernel(
    const float* __restrict__ dblp,  // (R,40): dt[0:8], B[8:24], C[24:40]
    const float* __restrict__ u,     // (R,256)
    const float* __restrict__ xz,    // (R,512): z at [256:512]
    const float* __restrict__ dt_w,  // (256,8)
    const float* __restrict__ dt_b,  // (256)
    const float* __restrict__ A_log, // (256,16)
    const float* __restrict__ Dp,    // (256)
    float* __restrict__ y,           // (R,256)
    int dir) {
  int b = blockIdx.x >> 4;
  int d0 = (blockIdx.x & 15) * 16;
  int tid = threadIdx.x;
  int s = tid & 15, dch = tid >> 4;

  __shared__ float del_s[64][16];
  __shared__ float u_s[64][16];
  __shared__ float B_s[64][16];
  __shared__ float C_s[64][16];
  __shared__ float y_s[64][16];
  __shared__ float dt_s[64][8];

  float A_ds = -__expf(A_log[(size_t)(d0 + dch) * 16 + s]);
  int col = tid & 15;  // channel role during load/epilogue phases
  float dtw_r[8];
#pragma unroll
  for (int r = 0; r < 8; ++r) dtw_r[r] = dt_w[(size_t)(d0 + col) * 8 + r];
  float dtb_c = dt_b[d0 + col];
  float Dp_c = Dp[d0 + col];
  float hstate = 0.f;
  size_t base_bl = (size_t)b * LSEQ;

  for (int c0 = 0; c0 < LSEQ; c0 += 64) {
    __syncthreads();  // previous epilogue done before overwriting LDS
    for (int i = tid; i < 64 * 16; i += 256) {
      int t = i >> 4, cc = i & 15;
      int tau = c0 + t;
      int l = dir ? (LSEQ - 1 - tau) : tau;
      size_t row = base_bl + l;
      u_s[t][cc] = u[row * 256 + d0 + cc];
      B_s[t][cc] = dblp[row * 40 + 8 + cc];
      C_s[t][cc] = dblp[row * 40 + 24 + cc];
    }
    for (int i = tid; i < 64 * 8; i += 256) {
      int t = i >> 3, r = i & 7;
      int tau = c0 + t;
      int l = dir ? (LSEQ - 1 - tau) : tau;
      dt_s[t][r] = dblp[(base_bl + l) * 40 + r];
    }
    __syncthreads();
    for (int i = tid; i < 64 * 16; i += 256) {
      int t = i >> 4;
      float acc = dtb_c;
#pragma unroll
      for (int r = 0; r < 8; ++r) acc += dt_s[t][r] * dtw_r[r];
      del_s[t][col] = (acc > 20.f) ? acc : log1pf(__expf(acc));
    }
    __syncthreads();
    for (int t = 0; t < 64; ++t) {
      float dl = del_s[t][dch];
      float a = __expf(dl * A_ds);
      hstate = a * hstate + dl * B_s[t][s] * u_s[t][dch];
      float p = hstate * C_s[t][s];
      p += __shfl_xor(p, 1);
      p += __shfl_xor(p, 2);
      p += __shfl_xor(p, 4);
      p += __shfl_xor(p, 8);
      if (s == 0) y_s[t][dch] = p;
    }
    __syncthreads();
    for (int i = tid; i < 64 * 16; i += 256) {
      int t = i >> 4, cc = i & 15;
      int tau = c0 + t;
      int l = dir ? (LSEQ - 1 - tau) : tau;
      size_t row = base_bl + l;
      float z = xz[row * 512 + 256 + d0 + cc];
      float yv = (y_s[t][cc] + u_s[t][cc] * Dp_c) * siluf(z);
      y[row * 256 + d0 + cc] = yv;
    }
  }
}

// tmp[row*128+c] = v * sigmoid(g), v = t[row*256+c], g = t[row*256+128+c]
__global__ __launch_bounds__(256) void glu_mult_kernel(
    const float* __restrict__ t, float* __restrict__ o) {
  size_t i = (size_t)blockIdx.x * 256 + threadIdx.x;
  size_t row = i >> 7;
  int c = (int)(i & 127);
  float v = t[row * 256 + c];
  float g = t[row * 256 + 128 + c];
  o[i] = v / (1.f + __expf(-g));
}

// ---------------------------------------------------------------------------
extern "C" void kernel_launch(void* const* d_in, const int* in_sizes, int n_in,
                              void* d_out, int out_size, void* d_ws, size_t ws_size,
                              hipStream_t stream) {
  const float* x = (const float*)d_in[0];
  const float* filt_w = (const float*)d_in[1];
  const float* filt_ln_w = (const float*)d_in[2];
  const float* filt_ln_b = (const float*)d_in[3];
  const float* F[11];
  const float* Bw[11];
  for (int i = 0; i < 11; ++i) {
    F[i] = (const float*)d_in[4 + i];
    Bw[i] = (const float*)d_in[15 + i];
  }
  const float* glu_fc1_w = (const float*)d_in[26];
  const float* glu_fc1_b = (const float*)d_in[27];
  const float* glu_fc2_w = (const float*)d_in[28];
  const float* glu_fc2_b = (const float*)d_in[29];
  const float* glu_ln_w = (const float*)d_in[30];
  const float* glu_ln_b = (const float*)d_in[31];

  // Per-batch workspace: h 128 + xz 512 + u 256 + dbl 40 + y 256 + fs 128
  // + bs 128 = 1448 floats/row * 2048 rows = 2,965,504 floats (~11.9 MB).
  // Choose the largest batch-chunk NB (divisor of 32) that fits ws_size.
  const size_t perBatch = 2048ull * 1448ull;
  size_t wsFloats = ws_size / 4;
  int NB = 32;
  while (NB > 1 && (size_t)NB * perBatch > wsFloats) NB >>= 1;
  const int nChunks = 32 / NB;
  const size_t R = (size_t)NB * LSEQ;  // rows per chunk

  float* ws = (float*)d_ws;
  float* h = ws;              // R*128
  float* xz = h + R * 128;    // R*512
  float* u = xz + R * 512;    // R*256
  float* dblb = u + R * 256;  // R*40
  float* y = dblb + R * 40;   // R*256
  float* fs = y + R * 256;    // R*128
  float* bs = fs + R * 128;   // R*128

  for (int ch = 0; ch < nChunks; ++ch) {
    const float* xc = x + (size_t)ch * NB * LSEQ * 128;
    float* outc = (float*)d_out + (size_t)ch * NB * LSEQ * 128;

    // FFT filter (+x residual) -> xz scratch; LN -> h
    fft_filter_kernel<<<NB * 128, 256, 0, stream>>>(xc, filt_w, xz);
    ln_kernel<<<R / 4, 256, 0, stream>>>(xz, nullptr, filt_ln_w, filt_ln_b, h, 1e-12f);

    for (int layer = 0; layer < 2; ++layer) {
      for (int dir = 0; dir < 2; ++dir) {
        const float* const* Wt = (dir == 0) ? F : Bw;
        const float* in_w = Wt[0] + (size_t)layer * 512 * 128;
        const float* conv_w = Wt[1] + (size_t)layer * 256 * 4;
        const float* conv_b = Wt[2] + (size_t)layer * 256;
        const float* xproj = Wt[3] + (size_t)layer * 40 * 256;
        const float* dt_w = Wt[4] + (size_t)layer * 256 * 8;
        const float* dt_b = Wt[5] + (size_t)layer * 256;
        const float* A_log = Wt[6] + (size_t)layer * 256 * 16;
        const float* Dp = Wt[7] + (size_t)layer * 256;
        const float* out_w = Wt[8] + (size_t)layer * 128 * 256;
        float* target = (dir == 0) ? fs : bs;

        gemm_kernel<<<dim3(8, R / 64), 256, 0, stream>>>(h, in_w, nullptr, xz, 512, 128);
        conv_silu_kernel<<<R, 256, 0, stream>>>(xz, conv_w, conv_b, u, dir);
        gemm_kernel<<<dim3(1, R / 64), 256, 0, stream>>>(u, xproj, nullptr, dblb, 40, 256);
        scan_kernel<<<NB * 16, 256, 0, stream>>>(dblb, u, xz, dt_w, dt_b, A_log, Dp, y, dir);
        gemm_kernel<<<dim3(2, R / 64), 256, 0, stream>>>(y, out_w, nullptr, target, 128, 256);
      }
      combine_ln_kernel<<<R / 4, 256, 0, stream>>>(
          h, fs, bs, F[9] + layer * 128, F[10] + layer * 128,
          Bw[9] + layer * 128, Bw[10] + layer * 128);
    }

    // GLU: t = h@fc1^T + b1 (into u); tmp = v*sigmoid(g) (into y);
    // gv = tmp@fc2^T + b2 (into fs); out = LN(gv + h)
    gemm_kernel<<<dim3(4, R / 64), 256, 0, stream>>>(h, glu_fc1_w, glu_fc1_b, u, 256, 128);
    glu_mult_kernel<<<R / 2, 256, 0, stream>>>(u, y);
    gemm_kernel<<<dim3(2, R / 64), 256, 0, stream>>>(y, glu_fc2_w, glu_fc2_b, fs, 128, 128);
    ln_kernel<<<R / 4, 256, 0, stream>>>(fs, h, glu_ln_w, glu_ln_b, outc, 1e-12f);
  }
}

// Round 5
// 3025.342 us; speedup vs baseline: 2.2400x; 2.2400x over previous
//
#include <hip/hip_runtime.h>
#include <cstddef>

#define LSEQ 2048
#define NCHUNK 8
#define CHLEN 256   // LSEQ / NCHUNK

typedef __attribute__((ext_vector_type(8))) short short8;
typedef __attribute__((ext_vector_type(4))) float floatx4;
typedef __attribute__((ext_vector_type(4))) unsigned short ushort4v;

static __device__ __forceinline__ float siluf(float x) { return x / (1.f + __expf(-x)); }

static __device__ __forceinline__ unsigned short f2bf(float f) {
  unsigned int u = __float_as_uint(f);
  u = (u + 0x7FFFu + ((u >> 16) & 1u)) >> 16;
  return (unsigned short)u;
}

// ---------------------------------------------------------------------------
// FFT filter kernel: per (b,d) channel, length-2048 complex FFT in LDS.
// Twiddles from a 1024-entry LDS table (e^{-2*pi*i*m/2048}), padded index.
// Forward DIF (natural -> bit-reversed), filter in bit-reversed order,
// inverse DIT (conjugate twiddles). Writes irfft(rfft(x)*W) + x.
// ---------------------------------------------------------------------------
__global__ __launch_bounds__(256) void fft_filter_kernel(
    const float* __restrict__ x, const float* __restrict__ filt_w,
    float* __restrict__ out) {
  int b = blockIdx.x >> 7, d = blockIdx.x & 127;
  __shared__ float2 A[2048];
  __shared__ float2 tw[1024 + 64];  // index m + (m>>4)
  const float* xp = x + (size_t)b * LSEQ * 128 + d;
  for (int i = threadIdx.x; i < 2048; i += 256) {
    A[i] = make_float2(xp[(size_t)i * 128], 0.f);
  }
  for (int i = threadIdx.x; i < 1024; i += 256) {
    float si, co;
    sincospif(-(float)i / 1024.f, &si, &co);
    tw[i + (i >> 4)] = make_float2(co, si);
  }
  // forward DIF
  for (int s = 11; s >= 1; --s) {
    int half = 1 << (s - 1);
    __syncthreads();
    for (int idx = threadIdx.x; idx < 1024; idx += 256) {
      int j = idx & (half - 1);
      int blk = idx >> (s - 1);
      int i0 = (blk << s) + j, i1 = i0 + half;
      int m = j << (11 - s);
      float2 w = tw[m + (m >> 4)];
      float co = w.x, si = w.y;
      float2 u = A[i0], v = A[i1];
      A[i0] = make_float2(u.x + v.x, u.y + v.y);
      float tx = u.x - v.x, ty = u.y - v.y;
      A[i1] = make_float2(tx * co - ty * si, tx * si + ty * co);
    }
  }
  __syncthreads();
  // filter multiply; storage index i holds X[rev(i)]
  for (int i = threadIdx.x; i < 2048; i += 256) {
    int k = (int)(__brev((unsigned)i) >> 21);
    float wr, wi;
    if (k <= 1024) {
      wr = filt_w[(size_t)k * 256 + d * 2];
      wi = filt_w[(size_t)k * 256 + d * 2 + 1];
    } else {
      int k2 = 2048 - k;
      wr = filt_w[(size_t)k2 * 256 + d * 2];
      wi = -filt_w[(size_t)k2 * 256 + d * 2 + 1];
    }
    float2 v = A[i];
    A[i] = make_float2(v.x * wr - v.y * wi, v.x * wi + v.y * wr);
  }
  // inverse DIT (conjugate twiddles)
  for (int s = 1; s <= 11; ++s) {
    int half = 1 << (s - 1);
    __syncthreads();
    for (int idx = threadIdx.x; idx < 1024; idx += 256) {
      int j = idx & (half - 1);
      int blk = idx >> (s - 1);
      int i0 = (blk << s) + j, i1 = i0 + half;
      int m = j << (11 - s);
      float2 w = tw[m + (m >> 4)];
      float co = w.x, si = -w.y;
      float2 u = A[i0], v = A[i1];
      float tx = v.x * co - v.y * si, ty = v.x * si + v.y * co;
      A[i0] = make_float2(u.x + tx, u.y + ty);
      A[i1] = make_float2(u.x - tx, u.y - ty);
    }
  }
  __syncthreads();
  const float inv_n = 1.f / 2048.f;
  for (int i = threadIdx.x; i < 2048; i += 256) {
    out[((size_t)b * LSEQ + i) * 128 + d] = A[i].x * inv_n + xp[(size_t)i * 128];
  }
}

// ---------------------------------------------------------------------------
// LayerNorm over 128 features; one wave per row. out = LN(x (+res)) * w + b
// ---------------------------------------------------------------------------
__global__ __launch_bounds__(256) void ln_kernel(
    const float* __restrict__ x, const float* __restrict__ res,
    const float* __restrict__ w, const float* __restrict__ b,
    float* __restrict__ out, float eps) {
  int row = blockIdx.x * 4 + (threadIdx.x >> 6);
  int lane = threadIdx.x & 63;
  size_t o = (size_t)row * 128;
  float v0 = x[o + lane], v1 = x[o + lane + 64];
  if (res) { v0 += res[o + lane]; v1 += res[o + lane + 64]; }
  float s = v0 + v1, q = v0 * v0 + v1 * v1;
  for (int ofs = 32; ofs > 0; ofs >>= 1) {
    s += __shfl_xor(s, ofs);
    q += __shfl_xor(q, ofs);
  }
  float mean = s * (1.f / 128.f);
  float var = q * (1.f / 128.f) - mean * mean;
  float inv = rsqrtf(var + eps);
  out[o + lane] = (v0 - mean) * inv * w[lane] + b[lane];
  out[o + lane + 64] = (v1 - mean) * inv * w[lane + 64] + b[lane + 64];
}

// h = LN(fs + h; fw,fb) + LN(bs + h; bw,bb), eps=1e-5, in place on h
__global__ __launch_bounds__(256) void combine_ln_kernel(
    float* __restrict__ h, const float* __restrict__ fs, const float* __restrict__ bs,
    const float* __restrict__ fw, const float* __restrict__ fb,
    const float* __restrict__ bw, const float* __restrict__ bb) {
  int row = blockIdx.x * 4 + (threadIdx.x >> 6);
  int lane = threadIdx.x & 63;
  size_t o = (size_t)row * 128;
  float h0 = h[o + lane], h1 = h[o + lane + 64];
  float f0 = fs[o + lane] + h0, f1 = fs[o + lane + 64] + h1;
  float g0 = bs[o + lane] + h0, g1 = bs[o + lane + 64] + h1;
  float s1 = f0 + f1, q1 = f0 * f0 + f1 * f1;
  float s2 = g0 + g1, q2 = g0 * g0 + g1 * g1;
  for (int ofs = 32; ofs > 0; ofs >>= 1) {
    s1 += __shfl_xor(s1, ofs); q1 += __shfl_xor(q1, ofs);
    s2 += __shfl_xor(s2, ofs); q2 += __shfl_xor(q2, ofs);
  }
  float m1 = s1 * (1.f / 128.f), v1 = q1 * (1.f / 128.f) - m1 * m1;
  float m2 = s2 * (1.f / 128.f), v2 = q2 * (1.f / 128.f) - m2 * m2;
  float i1 = rsqrtf(v1 + 1e-5f), i2 = rsqrtf(v2 + 1e-5f);
  h[o + lane] = (f0 - m1) * i1 * fw[lane] + fb[lane] +
                (g0 - m2) * i2 * bw[lane] + bb[lane];
  h[o + lane + 64] = (f1 - m1) * i1 * fw[lane + 64] + fb[lane + 64] +
                     (g1 - m2) * i2 * bw[lane + 64] + bb[lane + 64];
}

// ---------------------------------------------------------------------------
// bf16 MFMA GEMM: Out[R, N] = X[R, K] @ W[N, K]^T (+ bias), fp32 in/out.
// Tile BM=128 x BN=64, BK=32; 4 waves in 2x2; per-wave 64x32 (4x2 frags of
// 16x16x32). X/W staged to LDS as bf16 with stride 40 (16B-aligned rows,
// 2-way conflicts only). grid = (ceil(N/64), R/128).
// ---------------------------------------------------------------------------
__global__ __launch_bounds__(256) void gemm_bf16_kernel(
    const float* __restrict__ X, const float* __restrict__ W,
    const float* __restrict__ bias, float* __restrict__ Out, int N, int K) {
  __shared__ unsigned short Xs[128][40];
  __shared__ unsigned short Ws[64][40];
  int tid = threadIdx.x;
  int lane = tid & 63, wave = tid >> 6;
  int wm = wave >> 1, wn = wave & 1;
  int n0 = blockIdx.x * 64, m0 = blockIdx.y * 128;
  floatx4 acc[4][2] = {};

  int fr = lane & 15;              // fragment row (M for A, N for B)
  int fk = (lane >> 4) * 8;        // k offset within BK

  for (int k0 = 0; k0 < K; k0 += 32) {
    // stage X tile: 128 rows x 32 cols, 8 threads/row, float4 each
#pragma unroll
    for (int j = 0; j < 4; ++j) {
      int idx = tid + j * 256;
      int r = idx >> 3, c4 = (idx & 7) * 4;
      const float4 v = *(const float4*)&X[(size_t)(m0 + r) * K + k0 + c4];
      ushort4v h;
      h.x = f2bf(v.x); h.y = f2bf(v.y); h.z = f2bf(v.z); h.w = f2bf(v.w);
      *(ushort4v*)&Xs[r][c4] = h;
    }
    // stage W tile: 64 rows x 32 cols (zero-pad rows >= N)
#pragma unroll
    for (int j = 0; j < 2; ++j) {
      int idx = tid + j * 256;
      int r = idx >> 3, c4 = (idx & 7) * 4;
      int n = n0 + r;
      float4 v = make_float4(0.f, 0.f, 0.f, 0.f);
      if (n < N) v = *(const float4*)&W[(size_t)n * K + k0 + c4];
      ushort4v h;
      h.x = f2bf(v.x); h.y = f2bf(v.y); h.z = f2bf(v.z); h.w = f2bf(v.w);
      *(ushort4v*)&Ws[r][c4] = h;
    }
    __syncthreads();
    short8 a[4], bfrag[2];
#pragma unroll
    for (int m = 0; m < 4; ++m)
      a[m] = *(const short8*)&Xs[wm * 64 + m * 16 + fr][fk];
#pragma unroll
    for (int n = 0; n < 2; ++n)
      bfrag[n] = *(const short8*)&Ws[wn * 32 + n * 16 + fr][fk];
#pragma unroll
    for (int m = 0; m < 4; ++m)
#pragma unroll
      for (int n = 0; n < 2; ++n)
        acc[m][n] = __builtin_amdgcn_mfma_f32_16x16x32_bf16(
            a[m], bfrag[n], acc[m][n], 0, 0, 0);
    __syncthreads();
  }
  // epilogue: D mapping col=lane&15 (N), row=(lane>>4)*4+reg (M)
  int col = lane & 15, rbase = (lane >> 4) * 4;
#pragma unroll
  for (int n = 0; n < 2; ++n) {
    int nn = n0 + wn * 32 + n * 16 + col;
    if (nn >= N) continue;
    float bv = bias ? bias[nn] : 0.f;
#pragma unroll
    for (int m = 0; m < 4; ++m) {
      int mm = m0 + wm * 64 + m * 16 + rbase;
#pragma unroll
      for (int r = 0; r < 4; ++r) {
        Out[(size_t)(mm + r) * N + nn] = acc[m][n][r] + bv;
      }
    }
  }
}

// ---------------------------------------------------------------------------
// Causal depthwise conv(k=4) + bias + SiLU. dir=0: taps l-3+j ; dir=1: l+3-j
// xz layout (R, 512), channels 0..255 are xc. u layout (R, 256). grid = R.
// ---------------------------------------------------------------------------
__global__ __launch_bounds__(256) void conv_silu_kernel(
    const float* __restrict__ xz, const float* __restrict__ cw,
    const float* __restrict__ cb, float* __restrict__ u, int dir) {
  int idx = blockIdx.x * 256 + threadIdx.x;
  int c = idx & 255, bl = idx >> 8;
  int l = bl & (LSEQ - 1), b = bl >> 11;
  float acc = cb[c];
#pragma unroll
  for (int j = 0; j < 4; ++j) {
    int ln = dir ? (l + 3 - j) : (l - 3 + j);
    if (ln >= 0 && ln < LSEQ)
      acc += cw[c * 4 + j] * xz[((size_t)b * LSEQ + ln) * 512 + c];
  }
  u[(size_t)bl * 256 + c] = siluf(acc);
}

// ---------------------------------------------------------------------------
// Chunked selective scan.
// part1: per (b, dgroup, chunk) block, local scan from h=0 over CHLEN steps;
//        stores decay product P and local h_end (both 256 floats per block).
// carry: per (b, dgroup) block, composes chunk summaries into incoming
//        states Cbuf[chunk].
// part2: same traversal as part1 but starts from Cbuf and emits y with the
//        fused (+u*Dp)*silu(z) epilogue.
// Thread = (dch = tid>>4, s = tid&15) over a 16-channel group.
// ---------------------------------------------------------------------------
__global__ __launch_bounds__(256) void scan_part1_kernel(
    const float* __restrict__ dblp,  // (R,40): dt[0:8], B[8:24], C[24:40]
    const float* __restrict__ u,     // (R,256)
    const float* __restrict__ dt_w, const float* __restrict__ dt_b,
    const float* __restrict__ A_log,
    float* __restrict__ Pbuf, float* __restrict__ Hbuf, int dir) {
  int bid = blockIdx.x;
  int ch = bid & (NCHUNK - 1);
  int gdg = bid >> 3;              // b*16 + dgroup
  int b = gdg >> 4, dg = gdg & 15;
  int d0 = dg * 16;
  int tid = threadIdx.x;
  int s = tid & 15, dch = tid >> 4;

  __shared__ float del_s[64][16];
  __shared__ float u_s[64][16];
  __shared__ float B_s[64][16];
  __shared__ float dt_s[64][8];

  float A_ds = -__expf(A_log[(size_t)(d0 + dch) * 16 + s]);
  int col = tid & 15;
  float dtw_r[8];
#pragma unroll
  for (int r = 0; r < 8; ++r) dtw_r[r] = dt_w[(size_t)(d0 + col) * 8 + r];
  float dtb_c = dt_b[d0 + col];
  float hstate = 0.f, aprod = 1.f;
  size_t base_bl = (size_t)b * LSEQ;

  for (int c0 = ch * CHLEN; c0 < ch * CHLEN + CHLEN; c0 += 64) {
    __syncthreads();
    for (int i = tid; i < 64 * 16; i += 256) {
      int t = i >> 4, cc = i & 15;
      int tau = c0 + t;
      int l = dir ? (LSEQ - 1 - tau) : tau;
      size_t row = base_bl + l;
      u_s[t][cc] = u[row * 256 + d0 + cc];
      B_s[t][cc] = dblp[row * 40 + 8 + cc];
    }
    for (int i = tid; i < 64 * 8; i += 256) {
      int t = i >> 3, r = i & 7;
      int tau = c0 + t;
      int l = dir ? (LSEQ - 1 - tau) : tau;
      dt_s[t][r] = dblp[(base_bl + l) * 40 + r];
    }
    __syncthreads();
    for (int i = tid; i < 64 * 16; i += 256) {
      int t = i >> 4;
      float acc = dtb_c;
#pragma unroll
      for (int r = 0; r < 8; ++r) acc += dt_s[t][r] * dtw_r[r];
      del_s[t][col] = (acc > 20.f) ? acc : log1pf(__expf(acc));
    }
    __syncthreads();
    for (int t0 = 0; t0 < 64; t0 += 8) {
      float av[8], bv[8];
#pragma unroll
      for (int j = 0; j < 8; ++j) {
        float dl = del_s[t0 + j][dch];
        av[j] = __expf(dl * A_ds);
        bv[j] = dl * B_s[t0 + j][s] * u_s[t0 + j][dch];
      }
#pragma unroll
      for (int j = 0; j < 8; ++j) {
        hstate = av[j] * hstate + bv[j];
        aprod *= av[j];
      }
    }
  }
  size_t ib = ((size_t)gdg * NCHUNK + ch) * 256 + tid;
  Pbuf[ib] = aprod;
  Hbuf[ib] = hstate;
}

__global__ __launch_bounds__(256) void scan_carry_kernel(
    const float* __restrict__ Pbuf, const float* __restrict__ Hbuf,
    float* __restrict__ Cbuf) {
  int gdg = blockIdx.x;
  int tid = threadIdx.x;
  float carry = 0.f;
#pragma unroll
  for (int ch = 0; ch < NCHUNK; ++ch) {
    size_t ib = ((size_t)gdg * NCHUNK + ch) * 256 + tid;
    Cbuf[ib] = carry;
    carry = Pbuf[ib] * carry + Hbuf[ib];
  }
}

__global__ __launch_bounds__(256) void scan_part2_kernel(
    const float* __restrict__ dblp, const float* __restrict__ u,
    const float* __restrict__ xz,    // (R,512): z at [256:512]
    const float* __restrict__ dt_w, const float* __restrict__ dt_b,
    const float* __restrict__ A_log, const float* __restrict__ Dp,
    const float* __restrict__ Cbuf,
    float* __restrict__ y, int dir) {
  int bid = blockIdx.x;
  int ch = bid & (NCHUNK - 1);
  int gdg = bid >> 3;
  int b = gdg >> 4, dg = gdg & 15;
  int d0 = dg * 16;
  int tid = threadIdx.x;
  int s = tid & 15, dch = tid >> 4;

  __shared__ float del_s[64][16];
  __shared__ float u_s[64][16];
  __shared__ float B_s[64][16];
  __shared__ float C_s[64][16];
  __shared__ float y_s[64][16];
  __shared__ float dt_s[64][8];

  float A_ds = -__expf(A_log[(size_t)(d0 + dch) * 16 + s]);
  int col = tid & 15;
  float dtw_r[8];
#pragma unroll
  for (int r = 0; r < 8; ++r) dtw_r[r] = dt_w[(size_t)(d0 + col) * 8 + r];
  float dtb_c = dt_b[d0 + col];
  float Dp_c = Dp[d0 + col];
  float hstate = Cbuf[((size_t)gdg * NCHUNK + ch) * 256 + tid];
  size_t base_bl = (size_t)b * LSEQ;

  for (int c0 = ch * CHLEN; c0 < ch * CHLEN + CHLEN; c0 += 64) {
    __syncthreads();
    for (int i = tid; i < 64 * 16; i += 256) {
      int t = i >> 4, cc = i & 15;
      int tau = c0 + t;
      int l = dir ? (LSEQ - 1 - tau) : tau;
      size_t row = base_bl + l;
      u_s[t][cc] = u[row * 256 + d0 + cc];
      B_s[t][cc] = dblp[row * 40 + 8 + cc];
      C_s[t][cc] = dblp[row * 40 + 24 + cc];
    }
    for (int i = tid; i < 64 * 8; i += 256) {
      int t = i >> 3, r = i & 7;
      int tau = c0 + t;
      int l = dir ? (LSEQ - 1 - tau) : tau;
      dt_s[t][r] = dblp[(base_bl + l) * 40 + r];
    }
    __syncthreads();
    for (int i = tid; i < 64 * 16; i += 256) {
      int t = i >> 4;
      float acc = dtb_c;
#pragma unroll
      for (int r = 0; r < 8; ++r) acc += dt_s[t][r] * dtw_r[r];
      del_s[t][col] = (acc > 20.f) ? acc : log1pf(__expf(acc));
    }
    __syncthreads();
    for (int t0 = 0; t0 < 64; t0 += 8) {
      float av[8], bv[8], cs[8];
#pragma unroll
      for (int j = 0; j < 8; ++j) {
        float dl = del_s[t0 + j][dch];
        av[j] = __expf(dl * A_ds);
        bv[j] = dl * B_s[t0 + j][s] * u_s[t0 + j][dch];
        cs[j] = C_s[t0 + j][s];
      }
#pragma unroll
      for (int j = 0; j < 8; ++j) {
        hstate = av[j] * hstate + bv[j];
        float p = hstate * cs[j];
        p += __shfl_xor(p, 1);
        p += __shfl_xor(p, 2);
        p += __shfl_xor(p, 4);
        p += __shfl_xor(p, 8);
        if (s == 0) y_s[t0 + j][dch] = p;
      }
    }
    __syncthreads();
    for (int i = tid; i < 64 * 16; i += 256) {
      int t = i >> 4, cc = i & 15;
      int tau = c0 + t;
      int l = dir ? (LSEQ - 1 - tau) : tau;
      size_t row = base_bl + l;
      float z = xz[row * 512 + 256 + d0 + cc];
      float yv = (y_s[t][cc] + u_s[t][cc] * Dp_c) * siluf(z);
      y[row * 256 + d0 + cc] = yv;
    }
  }
}

// tmp[row*128+c] = v * sigmoid(g), v = t[row*256+c], g = t[row*256+128+c]
__global__ __launch_bounds__(256) void glu_mult_kernel(
    const float* __restrict__ t, float* __restrict__ o) {
  size_t i = (size_t)blockIdx.x * 256 + threadIdx.x;
  size_t row = i >> 7;
  int c = (int)(i & 127);
  float v = t[row * 256 + c];
  float g = t[row * 256 + 128 + c];
  o[i] = v / (1.f + __expf(-g));
}

// ---------------------------------------------------------------------------
extern "C" void kernel_launch(void* const* d_in, const int* in_sizes, int n_in,
                              void* d_out, int out_size, void* d_ws, size_t ws_size,
                              hipStream_t stream) {
  const float* x = (const float*)d_in[0];
  const float* filt_w = (const float*)d_in[1];
  const float* filt_ln_w = (const float*)d_in[2];
  const float* filt_ln_b = (const float*)d_in[3];
  const float* F[11];
  const float* Bw[11];
  for (int i = 0; i < 11; ++i) {
    F[i] = (const float*)d_in[4 + i];
    Bw[i] = (const float*)d_in[15 + i];
  }
  const float* glu_fc1_w = (const float*)d_in[26];
  const float* glu_fc1_b = (const float*)d_in[27];
  const float* glu_fc2_w = (const float*)d_in[28];
  const float* glu_fc2_b = (const float*)d_in[29];
  const float* glu_ln_w = (const float*)d_in[30];
  const float* glu_ln_b = (const float*)d_in[31];

  // Per-batch workspace: h 128 + xz 512 + u 256 + dbl 40 + y 256 + fs 128
  // + bs 128 = 1448 floats/row * 2048 rows, plus scan scratch
  // 3 * 16dg * 8ch * 256 = 98304 floats/batch.
  const size_t perBatch = 2048ull * 1448ull + 98304ull;
  size_t wsFloats = ws_size / 4;
  int NB = 32;
  while (NB > 1 && (size_t)NB * perBatch > wsFloats) NB >>= 1;
  const int nChunks = 32 / NB;
  const size_t R = (size_t)NB * LSEQ;  // rows per chunk

  float* ws = (float*)d_ws;
  float* h = ws;                 // R*128
  float* xz = h + R * 128;       // R*512
  float* u = xz + R * 512;       // R*256
  float* dblb = u + R * 256;     // R*40
  float* y = dblb + R * 40;      // R*256
  float* fs = y + R * 256;       // R*128
  float* bs = fs + R * 128;      // R*128
  float* Pbuf = bs + R * 128;    // NB*16*8*256
  float* Hbuf = Pbuf + (size_t)NB * 32768;
  float* Cbuf = Hbuf + (size_t)NB * 32768;

  for (int ch = 0; ch < nChunks; ++ch) {
    const float* xc = x + (size_t)ch * NB * LSEQ * 128;
    float* outc = (float*)d_out + (size_t)ch * NB * LSEQ * 128;

    // FFT filter (+x residual) -> xz scratch; LN -> h
    fft_filter_kernel<<<NB * 128, 256, 0, stream>>>(xc, filt_w, xz);
    ln_kernel<<<R / 4, 256, 0, stream>>>(xz, nullptr, filt_ln_w, filt_ln_b, h, 1e-12f);

    for (int layer = 0; layer < 2; ++layer) {
      for (int dir = 0; dir < 2; ++dir) {
        const float* const* Wt = (dir == 0) ? F : Bw;
        const float* in_w = Wt[0] + (size_t)layer * 512 * 128;
        const float* conv_w = Wt[1] + (size_t)layer * 256 * 4;
        const float* conv_b = Wt[2] + (size_t)layer * 256;
        const float* xproj = Wt[3] + (size_t)layer * 40 * 256;
        const float* dt_w = Wt[4] + (size_t)layer * 256 * 8;
        const float* dt_b = Wt[5] + (size_t)layer * 256;
        const float* A_log = Wt[6] + (size_t)layer * 256 * 16;
        const float* Dp = Wt[7] + (size_t)layer * 256;
        const float* out_w = Wt[8] + (size_t)layer * 128 * 256;
        float* target = (dir == 0) ? fs : bs;

        gemm_bf16_kernel<<<dim3(8, R / 128), 256, 0, stream>>>(h, in_w, nullptr, xz, 512, 128);
        conv_silu_kernel<<<R, 256, 0, stream>>>(xz, conv_w, conv_b, u, dir);
        gemm_bf16_kernel<<<dim3(1, R / 128), 256, 0, stream>>>(u, xproj, nullptr, dblb, 40, 256);
        scan_part1_kernel<<<NB * 16 * NCHUNK, 256, 0, stream>>>(
            dblb, u, dt_w, dt_b, A_log, Pbuf, Hbuf, dir);
        scan_carry_kernel<<<NB * 16, 256, 0, stream>>>(Pbuf, Hbuf, Cbuf);
        scan_part2_kernel<<<NB * 16 * NCHUNK, 256, 0, stream>>>(
            dblb, u, xz, dt_w, dt_b, A_log, Dp, Cbuf, y, dir);
        gemm_bf16_kernel<<<dim3(2, R / 128), 256, 0, stream>>>(y, out_w, nullptr, target, 128, 256);
      }
      combine_ln_kernel<<<R / 4, 256, 0, stream>>>(
          h, fs, bs, F[9] + layer * 128, F[10] + layer * 128,
          Bw[9] + layer * 128, Bw[10] + layer * 128);
    }

    // GLU: t = h@fc1^T + b1 (into u); tmp = v*sigmoid(g) (into y);
    // gv = tmp@fc2^T + b2 (into fs); out = LN(gv + h)
    gemm_bf16_kernel<<<dim3(4, R / 128), 256, 0, stream>>>(h, glu_fc1_w, glu_fc1_b, u, 256, 128);
    glu_mult_kernel<<<R / 2, 256, 0, stream>>>(u, y);
    gemm_bf16_kernel<<<dim3(2, R / 128), 256, 0, stream>>>(y, glu_fc2_w, glu_fc2_b, fs, 128, 128);
    ln_kernel<<<R / 4, 256, 0, stream>>>(fs, h, glu_ln_w, glu_ln_b, outc, 1e-12f);
  }
}

// Round 6
// 2999.185 us; speedup vs baseline: 2.2595x; 1.0087x over previous
//
#include <hip/hip_runtime.h>
#include <cstddef>

#define LSEQ 2048
#define NCHUNK 16
#define CHLEN 128   // LSEQ / NCHUNK

typedef __attribute__((ext_vector_type(8))) short short8;
typedef __attribute__((ext_vector_type(4))) float floatx4;
typedef __attribute__((ext_vector_type(4))) unsigned short ushort4v;

static __device__ __forceinline__ float siluf(float x) { return x / (1.f + __expf(-x)); }

static __device__ __forceinline__ unsigned short f2bf(float f) {
  unsigned int u = __float_as_uint(f);
  u = (u + 0x7FFFu + ((u >> 16) & 1u)) >> 16;
  return (unsigned short)u;
}

// ---------------------------------------------------------------------------
// FFT filter kernel (unchanged from round 5): per (b,d) channel, length-2048
// complex FFT in LDS with twiddle table. Writes irfft(rfft(x)*W) + x.
// ---------------------------------------------------------------------------
__global__ __launch_bounds__(256) void fft_filter_kernel(
    const float* __restrict__ x, const float* __restrict__ filt_w,
    float* __restrict__ out) {
  int b = blockIdx.x >> 7, d = blockIdx.x & 127;
  __shared__ float2 A[2048];
  __shared__ float2 tw[1024 + 64];  // index m + (m>>4)
  const float* xp = x + (size_t)b * LSEQ * 128 + d;
  for (int i = threadIdx.x; i < 2048; i += 256) {
    A[i] = make_float2(xp[(size_t)i * 128], 0.f);
  }
  for (int i = threadIdx.x; i < 1024; i += 256) {
    float si, co;
    sincospif(-(float)i / 1024.f, &si, &co);
    tw[i + (i >> 4)] = make_float2(co, si);
  }
  for (int s = 11; s >= 1; --s) {
    int half = 1 << (s - 1);
    __syncthreads();
    for (int idx = threadIdx.x; idx < 1024; idx += 256) {
      int j = idx & (half - 1);
      int blk = idx >> (s - 1);
      int i0 = (blk << s) + j, i1 = i0 + half;
      int m = j << (11 - s);
      float2 w = tw[m + (m >> 4)];
      float co = w.x, si = w.y;
      float2 u = A[i0], v = A[i1];
      A[i0] = make_float2(u.x + v.x, u.y + v.y);
      float tx = u.x - v.x, ty = u.y - v.y;
      A[i1] = make_float2(tx * co - ty * si, tx * si + ty * co);
    }
  }
  __syncthreads();
  for (int i = threadIdx.x; i < 2048; i += 256) {
    int k = (int)(__brev((unsigned)i) >> 21);
    float wr, wi;
    if (k <= 1024) {
      wr = filt_w[(size_t)k * 256 + d * 2];
      wi = filt_w[(size_t)k * 256 + d * 2 + 1];
    } else {
      int k2 = 2048 - k;
      wr = filt_w[(size_t)k2 * 256 + d * 2];
      wi = -filt_w[(size_t)k2 * 256 + d * 2 + 1];
    }
    float2 v = A[i];
    A[i] = make_float2(v.x * wr - v.y * wi, v.x * wi + v.y * wr);
  }
  for (int s = 1; s <= 11; ++s) {
    int half = 1 << (s - 1);
    __syncthreads();
    for (int idx = threadIdx.x; idx < 1024; idx += 256) {
      int j = idx & (half - 1);
      int blk = idx >> (s - 1);
      int i0 = (blk << s) + j, i1 = i0 + half;
      int m = j << (11 - s);
      float2 w = tw[m + (m >> 4)];
      float co = w.x, si = -w.y;
      float2 u = A[i0], v = A[i1];
      float tx = v.x * co - v.y * si, ty = v.x * si + v.y * co;
      A[i0] = make_float2(u.x + tx, u.y + ty);
      A[i1] = make_float2(u.x - tx, u.y - ty);
    }
  }
  __syncthreads();
  const float inv_n = 1.f / 2048.f;
  for (int i = threadIdx.x; i < 2048; i += 256) {
    out[((size_t)b * LSEQ + i) * 128 + d] = A[i].x * inv_n + xp[(size_t)i * 128];
  }
}

// ---------------------------------------------------------------------------
// LayerNorm over 128 features; one wave per row. out = LN(x (+res)) * w + b
// ---------------------------------------------------------------------------
__global__ __launch_bounds__(256) void ln_kernel(
    const float* __restrict__ x, const float* __restrict__ res,
    const float* __restrict__ w, const float* __restrict__ b,
    float* __restrict__ out, float eps) {
  int row = blockIdx.x * 4 + (threadIdx.x >> 6);
  int lane = threadIdx.x & 63;
  size_t o = (size_t)row * 128;
  float v0 = x[o + lane], v1 = x[o + lane + 64];
  if (res) { v0 += res[o + lane]; v1 += res[o + lane + 64]; }
  float s = v0 + v1, q = v0 * v0 + v1 * v1;
  for (int ofs = 32; ofs > 0; ofs >>= 1) {
    s += __shfl_xor(s, ofs);
    q += __shfl_xor(q, ofs);
  }
  float mean = s * (1.f / 128.f);
  float var = q * (1.f / 128.f) - mean * mean;
  float inv = rsqrtf(var + eps);
  out[o + lane] = (v0 - mean) * inv * w[lane] + b[lane];
  out[o + lane + 64] = (v1 - mean) * inv * w[lane + 64] + b[lane + 64];
}

// h = LN(fs + h; fw,fb) + LN(bs + h; bw,bb), eps=1e-5, in place on h
__global__ __launch_bounds__(256) void combine_ln_kernel(
    float* __restrict__ h, const float* __restrict__ fs, const float* __restrict__ bs,
    const float* __restrict__ fw, const float* __restrict__ fb,
    const float* __restrict__ bw, const float* __restrict__ bb) {
  int row = blockIdx.x * 4 + (threadIdx.x >> 6);
  int lane = threadIdx.x & 63;
  size_t o = (size_t)row * 128;
  float h0 = h[o + lane], h1 = h[o + lane + 64];
  float f0 = fs[o + lane] + h0, f1 = fs[o + lane + 64] + h1;
  float g0 = bs[o + lane] + h0, g1 = bs[o + lane + 64] + h1;
  float s1 = f0 + f1, q1 = f0 * f0 + f1 * f1;
  float s2 = g0 + g1, q2 = g0 * g0 + g1 * g1;
  for (int ofs = 32; ofs > 0; ofs >>= 1) {
    s1 += __shfl_xor(s1, ofs); q1 += __shfl_xor(q1, ofs);
    s2 += __shfl_xor(s2, ofs); q2 += __shfl_xor(q2, ofs);
  }
  float m1 = s1 * (1.f / 128.f), v1 = q1 * (1.f / 128.f) - m1 * m1;
  float m2 = s2 * (1.f / 128.f), v2 = q2 * (1.f / 128.f) - m2 * m2;
  float i1 = rsqrtf(v1 + 1e-5f), i2 = rsqrtf(v2 + 1e-5f);
  h[o + lane] = (f0 - m1) * i1 * fw[lane] + fb[lane] +
                (g0 - m2) * i2 * bw[lane] + bb[lane];
  h[o + lane + 64] = (f1 - m1) * i1 * fw[lane + 64] + fb[lane + 64] +
                     (g1 - m2) * i2 * bw[lane + 64] + bb[lane + 64];
}

// ---------------------------------------------------------------------------
// Wc[layer,dir] = dt_w @ xproj_dt  (256x256), so delta_lin = u @ Wc^T.
// grid (256 rows, 2 dirs, 2 layers), 256 threads = k.
// ---------------------------------------------------------------------------
__global__ __launch_bounds__(256) void wc_kernel(
    const float* __restrict__ fxp, const float* __restrict__ fdtw,
    const float* __restrict__ bxp, const float* __restrict__ bdtw,
    float* __restrict__ Wc) {
  int i = blockIdx.x, dir = blockIdx.y, layer = blockIdx.z, k = threadIdx.x;
  const float* xp = (dir ? bxp : fxp) + (size_t)layer * 40 * 256;
  const float* dtw = (dir ? bdtw : fdtw) + (size_t)layer * 256 * 8;
  float acc = 0.f;
#pragma unroll
  for (int r = 0; r < 8; ++r) acc += dtw[i * 8 + r] * xp[r * 256 + k];
  Wc[(((size_t)layer * 2 + dir) * 256 + i) * 256 + k] = acc;
}

// ---------------------------------------------------------------------------
// Generalized bf16 MFMA GEMM: Out[m, nn] = X[m, :] @ Wrow(nn)^T  (+epilogue)
// Wrow(nn) = (nn < nsplit) ? W0[nn] : W1[nn-nsplit];  W0/W1/bias/sp selected
// by blockIdx.z (a/b).  Epilogue: nn<nsplit -> +bias;  nn>=nsplit && sp ->
// softplus(acc + sp[nn-nsplit]).
// Tile 128x64, BK=32, 4 waves 2x2, per-wave 4x2 frags of 16x16x32 bf16.
// grid = (ceil(N/64), Mrows/128, nz).
// ---------------------------------------------------------------------------
__global__ __launch_bounds__(256) void gemm2_kernel(
    const float* __restrict__ X, int ldx, size_t xofs_z,
    const float* __restrict__ W0a, const float* __restrict__ W0b,
    const float* __restrict__ W1a, const float* __restrict__ W1b,
    int nsplit,
    const float* __restrict__ ba, const float* __restrict__ bb,
    const float* __restrict__ spa, const float* __restrict__ spb,
    float* __restrict__ Out, int ldo, size_t oofs_z,
    int N, int K) {
  int z = blockIdx.z;
  X += (size_t)z * xofs_z;
  Out += (size_t)z * oofs_z;
  const float* W0 = z ? W0b : W0a;
  const float* W1 = z ? W1b : W1a;
  const float* bias = z ? bb : ba;
  const float* sp = z ? spb : spa;

  __shared__ unsigned short Xs[128][40];
  __shared__ unsigned short Ws[64][40];
  int tid = threadIdx.x;
  int lane = tid & 63, wave = tid >> 6;
  int wm = wave >> 1, wn = wave & 1;
  int n0 = blockIdx.x * 64, m0 = blockIdx.y * 128;
  floatx4 acc[4][2] = {};

  int fr = lane & 15;
  int fk = (lane >> 4) * 8;

  for (int k0 = 0; k0 < K; k0 += 32) {
#pragma unroll
    for (int j = 0; j < 4; ++j) {
      int idx = tid + j * 256;
      int r = idx >> 3, c4 = (idx & 7) * 4;
      const float4 v = *(const float4*)&X[(size_t)(m0 + r) * ldx + k0 + c4];
      ushort4v hh;
      hh.x = f2bf(v.x); hh.y = f2bf(v.y); hh.z = f2bf(v.z); hh.w = f2bf(v.w);
      *(ushort4v*)&Xs[r][c4] = hh;
    }
#pragma unroll
    for (int j = 0; j < 2; ++j) {
      int idx = tid + j * 256;
      int r = idx >> 3, c4 = (idx & 7) * 4;
      int n = n0 + r;
      float4 v = make_float4(0.f, 0.f, 0.f, 0.f);
      if (n < N) {
        const float* wrow = (n < nsplit) ? &W0[(size_t)n * K]
                                         : &W1[(size_t)(n - nsplit) * K];
        v = *(const float4*)&wrow[k0 + c4];
      }
      ushort4v hh;
      hh.x = f2bf(v.x); hh.y = f2bf(v.y); hh.z = f2bf(v.z); hh.w = f2bf(v.w);
      *(ushort4v*)&Ws[r][c4] = hh;
    }
    __syncthreads();
    short8 a[4], bfrag[2];
#pragma unroll
    for (int m = 0; m < 4; ++m)
      a[m] = *(const short8*)&Xs[wm * 64 + m * 16 + fr][fk];
#pragma unroll
    for (int n = 0; n < 2; ++n)
      bfrag[n] = *(const short8*)&Ws[wn * 32 + n * 16 + fr][fk];
#pragma unroll
    for (int m = 0; m < 4; ++m)
#pragma unroll
      for (int n = 0; n < 2; ++n)
        acc[m][n] = __builtin_amdgcn_mfma_f32_16x16x32_bf16(
            a[m], bfrag[n], acc[m][n], 0, 0, 0);
    __syncthreads();
  }
  int col = lane & 15, rbase = (lane >> 4) * 4;
#pragma unroll
  for (int n = 0; n < 2; ++n) {
    int nn = n0 + wn * 32 + n * 16 + col;
    if (nn >= N) continue;
    float badd = 0.f;
    bool dosp = false;
    float spb_v = 0.f;
    if (nn < nsplit) {
      if (bias) badd = bias[nn];
    } else if (sp) {
      dosp = true;
      spb_v = sp[nn - nsplit];
    }
#pragma unroll
    for (int m = 0; m < 4; ++m) {
      int mm = m0 + wm * 64 + m * 16 + rbase;
#pragma unroll
      for (int r = 0; r < 4; ++r) {
        float v = acc[m][n][r];
        if (dosp) {
          float t = v + spb_v;
          v = (t > 20.f) ? t : log1pf(__expf(t));
        } else {
          v += badd;
        }
        Out[(size_t)(mm + r) * ldo + nn] = v;
      }
    }
  }
}

// ---------------------------------------------------------------------------
// Causal depthwise conv(k=4) + bias + SiLU, both dirs in one launch.
// xz layout (R, 1024): [xc_f(256) z_f(256) xc_b(256) z_b(256)].
// u layout (R, 512): [u_f(256) u_b(256)]. grid (R, 2).
// ---------------------------------------------------------------------------
__global__ __launch_bounds__(256) void conv_silu_kernel(
    const float* __restrict__ xz,
    const float* __restrict__ fcw, const float* __restrict__ fcb,
    const float* __restrict__ bcw, const float* __restrict__ bcb,
    float* __restrict__ u) {
  int bl = blockIdx.x, dir = blockIdx.y;
  int c = threadIdx.x;
  int l = bl & (LSEQ - 1), b = bl >> 11;
  const float* cw = dir ? bcw : fcw;
  const float* cb = dir ? bcb : fcb;
  float acc = cb[c];
#pragma unroll
  for (int j = 0; j < 4; ++j) {
    int ln = dir ? (l + 3 - j) : (l - 3 + j);
    if (ln >= 0 && ln < LSEQ)
      acc += cw[c * 4 + j] * xz[((size_t)b * LSEQ + ln) * 1024 + dir * 512 + c];
  }
  u[(size_t)bl * 512 + dir * 256 + c] = siluf(acc);
}

// ---------------------------------------------------------------------------
// Chunked selective scan, both dirs per launch (blockIdx.y = dir).
// dbl layout (2, R, 288): [B(16) C(16) delta(256)] (delta already softplus'd).
// part1: local scan from 0 -> (P, H) summary.  carry: compose.  part2: scan
// from carried state, emit y with fused (+u*Dp)*silu(z).
// Thread = (dch = tid>>4, s = tid&15) over a 16-channel group.
// ---------------------------------------------------------------------------
__global__ __launch_bounds__(256) void scan_part1_kernel(
    const float* __restrict__ dbl, const float* __restrict__ u,
    const float* __restrict__ Af, const float* __restrict__ Ab,
    float* __restrict__ Pbuf, float* __restrict__ Hbuf, size_t Rrows) {
  int dir = blockIdx.y;
  int bid = blockIdx.x;
  int ch = bid & (NCHUNK - 1);
  int gdg = bid >> 4;
  int G = gridDim.x >> 4;
  int b = gdg >> 4, dg = gdg & 15;
  int d0 = dg * 16;
  int tid = threadIdx.x;
  int s = tid & 15, dch = tid >> 4;

  __shared__ float del_s[64][16];
  __shared__ float u_s[64][16];
  __shared__ float B_s[64][16];

  const float* Alog = dir ? Ab : Af;
  float A_ds = -__expf(Alog[(size_t)(d0 + dch) * 16 + s]);
  float hstate = 0.f, aprod = 1.f;
  size_t base = (size_t)b * LSEQ;

  for (int c0 = ch * CHLEN; c0 < ch * CHLEN + CHLEN; c0 += 64) {
    __syncthreads();
    for (int i = tid; i < 1024; i += 256) {
      int t = i >> 4, cc = i & 15;
      int tau = c0 + t;
      int l = dir ? (LSEQ - 1 - tau) : tau;
      size_t row = base + l;
      u_s[t][cc] = u[row * 512 + dir * 256 + d0 + cc];
      size_t db = ((size_t)dir * Rrows + row) * 288;
      B_s[t][cc] = dbl[db + cc];
      del_s[t][cc] = dbl[db + 32 + d0 + cc];
    }
    __syncthreads();
    for (int t0 = 0; t0 < 64; t0 += 8) {
      float av[8], bv[8];
#pragma unroll
      for (int j = 0; j < 8; ++j) {
        float dl = del_s[t0 + j][dch];
        av[j] = __expf(dl * A_ds);
        bv[j] = dl * B_s[t0 + j][s] * u_s[t0 + j][dch];
      }
#pragma unroll
      for (int j = 0; j < 8; ++j) {
        hstate = av[j] * hstate + bv[j];
        aprod *= av[j];
      }
    }
  }
  size_t ib = (((size_t)dir * G + gdg) * NCHUNK + ch) * 256 + tid;
  Pbuf[ib] = aprod;
  Hbuf[ib] = hstate;
}

__global__ __launch_bounds__(256) void scan_carry_kernel(
    const float* __restrict__ Pbuf, const float* __restrict__ Hbuf,
    float* __restrict__ Cbuf) {
  int gdg = blockIdx.x, dir = blockIdx.y;
  int G = gridDim.x;
  int tid = threadIdx.x;
  float carry = 0.f;
#pragma unroll
  for (int ch = 0; ch < NCHUNK; ++ch) {
    size_t ib = (((size_t)dir * G + gdg) * NCHUNK + ch) * 256 + tid;
    Cbuf[ib] = carry;
    carry = Pbuf[ib] * carry + Hbuf[ib];
  }
}

__global__ __launch_bounds__(256) void scan_part2_kernel(
    const float* __restrict__ dbl, const float* __restrict__ u,
    const float* __restrict__ xz,
    const float* __restrict__ Af, const float* __restrict__ Ab,
    const float* __restrict__ Dpf, const float* __restrict__ Dpb,
    const float* __restrict__ Cbuf,
    float* __restrict__ y, size_t Rrows) {
  int dir = blockIdx.y;
  int bid = blockIdx.x;
  int ch = bid & (NCHUNK - 1);
  int gdg = bid >> 4;
  int G = gridDim.x >> 4;
  int b = gdg >> 4, dg = gdg & 15;
  int d0 = dg * 16;
  int tid = threadIdx.x;
  int s = tid & 15, dch = tid >> 4;

  __shared__ float del_s[64][16];
  __shared__ float u_s[64][16];
  __shared__ float B_s[64][16];
  __shared__ float C_s[64][16];
  __shared__ float y_s[64][16];

  const float* Alog = dir ? Ab : Af;
  float A_ds = -__expf(Alog[(size_t)(d0 + dch) * 16 + s]);
  float Dp_c = (dir ? Dpb : Dpf)[d0 + (tid & 15)];
  float hstate = Cbuf[(((size_t)dir * G + gdg) * NCHUNK + ch) * 256 + tid];
  size_t base = (size_t)b * LSEQ;

  for (int c0 = ch * CHLEN; c0 < ch * CHLEN + CHLEN; c0 += 64) {
    __syncthreads();
    for (int i = tid; i < 1024; i += 256) {
      int t = i >> 4, cc = i & 15;
      int tau = c0 + t;
      int l = dir ? (LSEQ - 1 - tau) : tau;
      size_t row = base + l;
      u_s[t][cc] = u[row * 512 + dir * 256 + d0 + cc];
      size_t db = ((size_t)dir * Rrows + row) * 288;
      B_s[t][cc] = dbl[db + cc];
      C_s[t][cc] = dbl[db + 16 + cc];
      del_s[t][cc] = dbl[db + 32 + d0 + cc];
    }
    __syncthreads();
    for (int t0 = 0; t0 < 64; t0 += 8) {
      float av[8], bv[8], cs[8];
#pragma unroll
      for (int j = 0; j < 8; ++j) {
        float dl = del_s[t0 + j][dch];
        av[j] = __expf(dl * A_ds);
        bv[j] = dl * B_s[t0 + j][s] * u_s[t0 + j][dch];
        cs[j] = C_s[t0 + j][s];
      }
#pragma unroll
      for (int j = 0; j < 8; ++j) {
        hstate = av[j] * hstate + bv[j];
        float p = hstate * cs[j];
        p += __shfl_xor(p, 1);
        p += __shfl_xor(p, 2);
        p += __shfl_xor(p, 4);
        p += __shfl_xor(p, 8);
        if (s == 0) y_s[t0 + j][dch] = p;
      }
    }
    __syncthreads();
    for (int i = tid; i < 1024; i += 256) {
      int t = i >> 4, cc = i & 15;
      int tau = c0 + t;
      int l = dir ? (LSEQ - 1 - tau) : tau;
      size_t row = base + l;
      float z = xz[row * 1024 + dir * 512 + 256 + d0 + cc];
      float yv = (y_s[t][cc] + u_s[t][cc] * Dp_c) * siluf(z);
      y[((size_t)dir * Rrows + row) * 256 + d0 + cc] = yv;
    }
  }
}

// tmp[row*128+c] = v * sigmoid(g); t layout (R,256): v=[0:128], g=[128:256]
__global__ __launch_bounds__(256) void glu_mult_kernel(
    const float* __restrict__ t, float* __restrict__ o) {
  size_t i = (size_t)blockIdx.x * 256 + threadIdx.x;
  size_t row = i >> 7;
  int c = (int)(i & 127);
  float v = t[row * 256 + c];
  float g = t[row * 256 + 128 + c];
  o[i] = v / (1.f + __expf(-g));
}

// ---------------------------------------------------------------------------
extern "C" void kernel_launch(void* const* d_in, const int* in_sizes, int n_in,
                              void* d_out, int out_size, void* d_ws, size_t ws_size,
                              hipStream_t stream) {
  const float* x = (const float*)d_in[0];
  const float* filt_w = (const float*)d_in[1];
  const float* filt_ln_w = (const float*)d_in[2];
  const float* filt_ln_b = (const float*)d_in[3];
  const float* F[11];
  const float* Bw[11];
  for (int i = 0; i < 11; ++i) {
    F[i] = (const float*)d_in[4 + i];
    Bw[i] = (const float*)d_in[15 + i];
  }
  const float* glu_fc1_w = (const float*)d_in[26];
  const float* glu_fc1_b = (const float*)d_in[27];
  const float* glu_fc2_w = (const float*)d_in[28];
  const float* glu_fc2_b = (const float*)d_in[29];
  const float* glu_ln_w = (const float*)d_in[30];
  const float* glu_ln_b = (const float*)d_in[31];

  // Workspace: Wc (4*65536, shared) + per batch:
  // h 128 + xz 1024 + u 512 + dbl 576 + y 512 + fsbs 256 = 3008 fl/row * 2048
  // + scan P/H/C 3 * 2*16*16*256 = 393216 -> 6,553,600 floats (~26.2 MB)/batch
  const size_t wcFloats = 262144;
  const size_t perBatch = 2048ull * 3008ull + 393216ull;
  size_t wsFloats = ws_size / 4;
  int NB = 32;
  while (NB > 1 && wcFloats + (size_t)NB * perBatch > wsFloats) NB >>= 1;
  const int nChunks = 32 / NB;
  const size_t R = (size_t)NB * LSEQ;  // rows per chunk
  const int G = NB * 16;               // (batch, dgroup) pairs

  float* ws = (float*)d_ws;
  float* Wc = ws;                   // 4 * 256*256
  float* h = Wc + wcFloats;         // R*128
  float* xz = h + R * 128;          // R*1024
  float* u = xz + R * 1024;         // R*512
  float* dbl = u + R * 512;         // 2*R*288
  float* y = dbl + R * 576;         // 2*R*256
  float* fsbs = y + R * 512;        // 2*R*128
  float* Pbuf = fsbs + R * 256;     // 2*G*16*256
  float* Hbuf = Pbuf + (size_t)G * 8192;
  float* Cbuf = Hbuf + (size_t)G * 8192;

  // Precompute Wc for all (layer, dir)
  wc_kernel<<<dim3(256, 2, 2), 256, 0, stream>>>(F[3], F[4], Bw[3], Bw[4], Wc);

  for (int ch = 0; ch < nChunks; ++ch) {
    const float* xc = x + (size_t)ch * NB * LSEQ * 128;
    float* outc = (float*)d_out + (size_t)ch * NB * LSEQ * 128;

    // FFT filter (+x residual) -> xz scratch (R*128 region); LN -> h
    fft_filter_kernel<<<NB * 128, 256, 0, stream>>>(xc, filt_w, xz);
    ln_kernel<<<R / 4, 256, 0, stream>>>(xz, nullptr, filt_ln_w, filt_ln_b, h, 1e-12f);

    for (int layer = 0; layer < 2; ++layer) {
      const float* f_in = F[0] + (size_t)layer * 512 * 128;
      const float* b_in = Bw[0] + (size_t)layer * 512 * 128;
      const float* f_cw = F[1] + (size_t)layer * 256 * 4;
      const float* b_cw = Bw[1] + (size_t)layer * 256 * 4;
      const float* f_cb = F[2] + (size_t)layer * 256;
      const float* b_cb = Bw[2] + (size_t)layer * 256;
      const float* f_xpBC = F[3] + (size_t)layer * 40 * 256 + 8 * 256;
      const float* b_xpBC = Bw[3] + (size_t)layer * 40 * 256 + 8 * 256;
      const float* WcF = Wc + (size_t)(layer * 2 + 0) * 65536;
      const float* WcB = Wc + (size_t)(layer * 2 + 1) * 65536;
      const float* f_dtb = F[5] + (size_t)layer * 256;
      const float* b_dtb = Bw[5] + (size_t)layer * 256;
      const float* f_A = F[6] + (size_t)layer * 256 * 16;
      const float* b_A = Bw[6] + (size_t)layer * 256 * 16;
      const float* f_Dp = F[7] + (size_t)layer * 256;
      const float* b_Dp = Bw[7] + (size_t)layer * 256;
      const float* f_ow = F[8] + (size_t)layer * 128 * 256;
      const float* b_ow = Bw[8] + (size_t)layer * 128 * 256;

      // in-proj: xz[R,1024] = h @ [f_in; b_in]^T  (n<512 -> f, else b)
      gemm2_kernel<<<dim3(16, R / 128, 1), 256, 0, stream>>>(
          h, 128, 0, f_in, nullptr, b_in, nullptr, 512,
          nullptr, nullptr, nullptr, nullptr, xz, 1024, 0, 1024, 128);
      // conv+silu both dirs -> u[R,512]
      conv_silu_kernel<<<dim3(R, 2), 256, 0, stream>>>(xz, f_cw, f_cb, b_cw, b_cb, u);
      // xproj: dbl[2,R,288] = [B C softplus(delta_lin+dt_b)]
      gemm2_kernel<<<dim3(5, R / 128, 2), 256, 0, stream>>>(
          u, 512, 256, f_xpBC, b_xpBC, WcF, WcB, 32,
          nullptr, nullptr, f_dtb, b_dtb, dbl, 288, R * 288, 288, 256);
      // chunked scan
      scan_part1_kernel<<<dim3(G * NCHUNK, 2), 256, 0, stream>>>(
          dbl, u, f_A, b_A, Pbuf, Hbuf, R);
      scan_carry_kernel<<<dim3(G, 2), 256, 0, stream>>>(Pbuf, Hbuf, Cbuf);
      scan_part2_kernel<<<dim3(G * NCHUNK, 2), 256, 0, stream>>>(
          dbl, u, xz, f_A, b_A, f_Dp, b_Dp, Cbuf, y, R);
      // out-proj: fsbs[2,R,128] = y @ out_w^T  (z-selected weights)
      gemm2_kernel<<<dim3(2, R / 128, 2), 256, 0, stream>>>(
          y, 256, R * 256, f_ow, b_ow, nullptr, nullptr, 128,
          nullptr, nullptr, nullptr, nullptr, fsbs, 128, R * 128, 128, 256);
      combine_ln_kernel<<<R / 4, 256, 0, stream>>>(
          h, fsbs, fsbs + R * 128, F[9] + layer * 128, F[10] + layer * 128,
          Bw[9] + layer * 128, Bw[10] + layer * 128);
    }

    // GLU: t = h@fc1^T+b1 -> y(R,256); tmp=v*sig(g) -> u(R,128);
    // gv = tmp@fc2^T+b2 -> fsbs; out = LN(gv + h)
    gemm2_kernel<<<dim3(4, R / 128, 1), 256, 0, stream>>>(
        h, 128, 0, glu_fc1_w, nullptr, nullptr, nullptr, 256,
        glu_fc1_b, nullptr, nullptr, nullptr, y, 256, 0, 256, 128);
    glu_mult_kernel<<<R / 2, 256, 0, stream>>>(y, u);
    gemm2_kernel<<<dim3(2, R / 128, 1), 256, 0, stream>>>(
        u, 128, 0, glu_fc2_w, nullptr, nullptr, nullptr, 128,
        glu_fc2_b, nullptr, nullptr, nullptr, fsbs, 128, 0, 128, 128);
    ln_kernel<<<R / 4, 256, 0, stream>>>(fsbs, h, glu_ln_w, glu_ln_b, outc, 1e-12f);
  }
}